// Round 5
// baseline (88.789 us; speedup 1.0000x reference)
//
#include <hip/hip_runtime.h>

typedef __attribute__((ext_vector_type(8))) __bf16  bf16x8;
typedef __attribute__((ext_vector_type(8))) short   short8;
typedef __attribute__((ext_vector_type(4))) float   f32x4;

#define DM   512
#define BM   256
#define BN   256
#define BK   64
#define NNT  2                 // n-tiles (512/256)
#define NKT  8                 // k-tiles (512/64)
#define TILEB 32768            // bytes per B tile image (256x64 bf16)

__device__ __forceinline__ short f2bf(float f) {
  union { float f; unsigned u; } v; v.f = f;
  unsigned r = v.u + 0x7fffu + ((v.u >> 16) & 1u);   // RNE
  return (short)(r >> 16);
}

// XOR swizzle within a [rows][64 bf16] tile (128B row stride).
__device__ __forceinline__ int swz(int r, int cbyte) {
  return (r * 128 + cbyte) ^ ((r & 7) << 4);
}

// Fold softmax(taps) + conv into per-head G[h][e][d], stored as pre-swizzled
// per-(h,nt,kt) 256x64 LDS tile images. Vectorized: 8 d's per thread.
__global__ void build_g_kernel(const float* __restrict__ w,
                               const float* __restrict__ fcw,
                               short* __restrict__ Gt) {
  int idx = blockIdx.x * 256 + threadIdx.x;   // 8*512*512/8 = 256K threads
  int h  = idx >> 15;
  int t  = idx & 32767;
  int e  = t >> 6;
  int d0 = (t & 63) << 3;
  float w0 = w[h*3+0], w1 = w[h*3+1], w2 = w[h*3+2];
  float mx = fmaxf(w0, fmaxf(w1, w2));
  float e0 = __expf(w0-mx), e1 = __expf(w1-mx), e2 = __expf(w2-mx);
  float inv = 1.0f / (e0 + e1 + e2);
  float w0n = e0*inv, w1n = e1*inv, w2n = e2*inv;
  const float* row = fcw + e * DM;
  float v[10];
  v[0] = (d0 > 0) ? row[d0-1] : 0.0f;          // left edge: tap dropped
  float4 a = *(const float4*)(row + d0);
  float4 b = *(const float4*)(row + d0 + 4);
  v[1]=a.x; v[2]=a.y; v[3]=a.z; v[4]=a.w;
  v[5]=b.x; v[6]=b.y; v[7]=b.z; v[8]=b.w;
  v[9] = (d0 + 8 < DM) ? row[d0+8] : 0.0f;     // right edge
  short8 sv;
  #pragma unroll
  for (int j = 0; j < 8; ++j)
    sv[j] = f2bf(w1n*v[j+1] + w0n*v[j+2] + w2n*v[j]);
  int nt = e >> 8, r = e & 255;
  int kt = d0 >> 6, c = d0 & 63;
  char* tile = (char*)Gt + (size_t)((h * NNT + nt) * NKT + kt) * TILEB;
  *(short8*)(tile + swz(r, c * 2)) = sv;
}

// y[R,e] = sum_d x[R,d] * G[R%8][e,d]; R = h + 8*t
__global__ __launch_bounds__(512, 2) void gemm_kernel(const float* __restrict__ x,
                                                      const short* __restrict__ Gt,
                                                      float* __restrict__ out) {
  int bid = blockIdx.x;          // 512 blocks
  int h  = bid & 7;              // head == XCD
  int nt = (bid >> 3) & 1;
  int mt = bid >> 4;
  int tid  = threadIdx.x;
  int lane = tid & 63;
  int wid  = tid >> 6;
  int wr = wid >> 2, wc = wid & 3;   // 2x4 wave grid, 128x64 per wave

  __shared__ short Alds[2][BM * BK];   // 2 x 32 KiB swizzled
  __shared__ short Blds[2][BN * BK];   // 2 x 32 KiB swizzled

  const char* Bsrc0 = (const char*)Gt + (size_t)(h * NNT + nt) * NKT * TILEB;
  const float* Abase = x + (size_t)(h + 8 * (size_t)mt * BM) * DM;

  float4 ap[8];   // A prefetch regs

  auto loadA = [&](int kt) {
    #pragma unroll
    for (int p = 0; p < 4; ++p) {
      int r = (tid >> 3) + 64 * p;
      const float* xr = Abase + (size_t)r * 8 * DM + kt * BK + (tid & 7) * 8;
      ap[2*p]   = *(const float4*)xr;
      ap[2*p+1] = *(const float4*)(xr + 4);
    }
  };
  auto stageB = [&](int kt, int buf) {
    const char* src = Bsrc0 + kt * TILEB;
    char* dst = (char*)Blds[buf];
    #pragma unroll
    for (int p = 0; p < 4; ++p)
      __builtin_amdgcn_global_load_lds((const void*)(src + p * 8192 + tid * 16),
                                       (void*)(dst + p * 8192 + wid * 1024), 16, 0, 0);
  };
  auto writeA = [&](int buf) {
    char* dst = (char*)Alds[buf];
    #pragma unroll
    for (int p = 0; p < 4; ++p) {
      int r = (tid >> 3) + 64 * p;
      short8 sv;
      sv[0]=f2bf(ap[2*p].x);   sv[1]=f2bf(ap[2*p].y);
      sv[2]=f2bf(ap[2*p].z);   sv[3]=f2bf(ap[2*p].w);
      sv[4]=f2bf(ap[2*p+1].x); sv[5]=f2bf(ap[2*p+1].y);
      sv[6]=f2bf(ap[2*p+1].z); sv[7]=f2bf(ap[2*p+1].w);
      *(short8*)(dst + swz(r, (tid & 7) * 16)) = sv;
    }
  };

  f32x4 acc[8][4] = {};   // wave tile 128x64

  auto rdA = [&](bf16x8* af, const char* Ap, int mh, int ks) {
    #pragma unroll
    for (int m = 0; m < 4; ++m)
      af[m] = *(const bf16x8*)(Ap + swz(wr*128 + (mh*4 + m)*16 + (lane & 15),
                                        ks*64 + (lane >> 4) * 16));
  };
  auto rdB = [&](bf16x8* bfr, const char* Bp, int ks) {
    #pragma unroll
    for (int n = 0; n < 4; ++n)
      bfr[n] = *(const bf16x8*)(Bp + swz(wc*64 + n*16 + (lane & 15),
                                         ks*64 + (lane >> 4) * 16));
  };
  auto mma16 = [&](bf16x8* af, bf16x8* bfr, int mh) {
    #pragma unroll
    for (int m = 0; m < 4; ++m)
      #pragma unroll
      for (int n = 0; n < 4; ++n)
        acc[mh*4 + m][n] = __builtin_amdgcn_mfma_f32_16x16x32_bf16(af[m], bfr[n],
                                                                   acc[mh*4 + m][n], 0, 0, 0);
  };

#define SBAR()  do { __builtin_amdgcn_s_barrier(); __builtin_amdgcn_sched_barrier(0); } while (0)
#define LGKM0() do { asm volatile("s_waitcnt lgkmcnt(0)" ::: "memory"); \
                     __builtin_amdgcn_sched_barrier(0); } while (0)

  // prologue: tile 0 -> buf 0
  loadA(0);
  stageB(0, 0);
  writeA(0);              // compiler waits vmcnt(4) for ap
  __syncthreads();        // drains vmcnt+lgkm

  for (int kt = 0; kt < NKT; ++kt) {
    int nxt = (kt & 1) ^ 1;
    const char* Ap = (const char*)Alds[kt & 1];
    const char* Bp = (const char*)Blds[kt & 1];
    bool pre = (kt + 1 < NKT);
    bf16x8 af[4], bf0[4];

    // phase 0: reads(mh0,ks0)+B(ks0) | issue loadA(kt+1)
    rdB(bf0, Bp, 0); rdA(af, Ap, 0, 0);
    if (pre) loadA(kt + 1);
    SBAR(); LGKM0();
    __builtin_amdgcn_s_setprio(1); mma16(af, bf0, 0); __builtin_amdgcn_s_setprio(0);
    SBAR();

    // phase 1: reads(mh1,ks0) | issue stageB(kt+1)
    rdA(af, Ap, 1, 0);
    if (pre) stageB(kt + 1, nxt);
    SBAR(); LGKM0();
    __builtin_amdgcn_s_setprio(1); mma16(af, bf0, 1); __builtin_amdgcn_s_setprio(0);
    SBAR();

    // phase 2: reads(mh0,ks1)+B(ks1)
    rdB(bf0, Bp, 1); rdA(af, Ap, 0, 1);
    SBAR(); LGKM0();
    __builtin_amdgcn_s_setprio(1); mma16(af, bf0, 0); __builtin_amdgcn_s_setprio(0);
    SBAR();

    // phase 3: reads(mh1,ks1) | convert+writeA after MFMA
    rdA(af, Ap, 1, 1);
    SBAR(); LGKM0();
    __builtin_amdgcn_s_setprio(1); mma16(af, bf0, 1); __builtin_amdgcn_s_setprio(0);
    if (pre) writeA(nxt);   // compiler: vmcnt(4) for ap (issued @p0, ~3 phases old)
    __syncthreads();        // boundary: drains stageB (issued @p1) + ds_writes
  }

  // epilogue: C/D layout col = lane&15, row = (lane>>4)*4 + j
  int e0 = nt * BN + wc * 64 + (lane & 15);
  #pragma unroll
  for (int m = 0; m < 8; ++m) {
    int tq = mt * BM + wr * 128 + m * 16 + ((lane >> 4) << 2);
    #pragma unroll
    for (int j = 0; j < 4; ++j) {
      int R = h + 8 * (tq + j);
      float* orow = out + (size_t)R * DM + e0;
      #pragma unroll
      for (int n = 0; n < 4; ++n)
        orow[n * 16] = acc[m][n][j];
    }
  }
#undef SBAR
#undef LGKM0
}

extern "C" void kernel_launch(void* const* d_in, const int* in_sizes, int n_in,
                              void* d_out, int out_size, void* d_ws, size_t ws_size,
                              hipStream_t stream) {
  const float* x   = (const float*)d_in[0];
  const float* w   = (const float*)d_in[1];
  const float* fcw = (const float*)d_in[2];
  float* out = (float*)d_out;
  short* Gt  = (short*)d_ws;   // 4 MiB pre-swizzled tile images

  hipLaunchKernelGGL(build_g_kernel, dim3((8 * DM * DM / 8) / 256), dim3(256), 0, stream,
                     w, fcw, Gt);
  hipLaunchKernelGGL(gemm_kernel, dim3(8 * 32 * NNT), dim3(512), 0, stream,
                     x, Gt, out);
}

// Round 6
// 85.242 us; speedup vs baseline: 1.0416x; 1.0416x over previous
//
#include <hip/hip_runtime.h>

typedef __attribute__((ext_vector_type(8))) __bf16  bf16x8;
typedef __attribute__((ext_vector_type(8))) short   short8;
typedef __attribute__((ext_vector_type(4))) float   f32x4;

#define DM   512
#define BM   256
#define BN   256
#define BK   64
#define NNT  2                 // n-tiles (512/256)
#define NKT  8                 // k-tiles (512/64)
#define TILEB 32768            // bytes per B tile image (256x64 bf16)

__device__ __forceinline__ short f2bf(float f) {
  union { float f; unsigned u; } v; v.f = f;
  unsigned r = v.u + 0x7fffu + ((v.u >> 16) & 1u);   // RNE
  return (short)(r >> 16);
}

// XOR swizzle within a [rows][64 bf16] tile (128B row stride).
__device__ __forceinline__ int swz(int r, int cbyte) {
  return (r * 128 + cbyte) ^ ((r & 7) << 4);
}

// Fold softmax(taps) + conv into per-head G[h][e][d], stored as pre-swizzled
// per-(h,nt,kt) 256x64 LDS tile images. Vectorized: 8 d's per thread.
__global__ void build_g_kernel(const float* __restrict__ w,
                               const float* __restrict__ fcw,
                               short* __restrict__ Gt) {
  int idx = blockIdx.x * 256 + threadIdx.x;   // 8*512*512/8 threads
  int h  = idx >> 15;
  int t  = idx & 32767;
  int e  = t >> 6;
  int d0 = (t & 63) << 3;
  float w0 = w[h*3+0], w1 = w[h*3+1], w2 = w[h*3+2];
  float mx = fmaxf(w0, fmaxf(w1, w2));
  float e0 = __expf(w0-mx), e1 = __expf(w1-mx), e2 = __expf(w2-mx);
  float inv = 1.0f / (e0 + e1 + e2);
  float w0n = e0*inv, w1n = e1*inv, w2n = e2*inv;
  const float* row = fcw + e * DM;
  float v[10];
  v[0] = (d0 > 0) ? row[d0-1] : 0.0f;
  float4 a = *(const float4*)(row + d0);
  float4 b = *(const float4*)(row + d0 + 4);
  v[1]=a.x; v[2]=a.y; v[3]=a.z; v[4]=a.w;
  v[5]=b.x; v[6]=b.y; v[7]=b.z; v[8]=b.w;
  v[9] = (d0 + 8 < DM) ? row[d0+8] : 0.0f;
  short8 sv;
  #pragma unroll
  for (int j = 0; j < 8; ++j)
    sv[j] = f2bf(w1n*v[j+1] + w0n*v[j+2] + w2n*v[j]);
  int nt = e >> 8, r = e & 255;
  int kt = d0 >> 6, c = d0 & 63;
  char* tile = (char*)Gt + (size_t)((h * NNT + nt) * NKT + kt) * TILEB;
  *(short8*)(tile + swz(r, c * 2)) = sv;
}

// y[R,e] = sum_d x[R,d] * G[R%8][e,d]; R = h + 8*t
__global__ __launch_bounds__(512, 2) void gemm_kernel(const float* __restrict__ x,
                                                      const short* __restrict__ Gt,
                                                      float* __restrict__ out) {
  int bid = blockIdx.x;          // 512 blocks
  int h  = bid & 7;              // head == XCD
  int nt = (bid >> 3) & 1;
  int mt = bid >> 4;
  int tid  = threadIdx.x;
  int lane = tid & 63;
  int wid  = tid >> 6;
  int wr = wid >> 2, wc = wid & 3;   // 2x4 wave grid, 128x64 per wave

  __shared__ short Alds[2][BM * BK];   // 2 x 32 KiB swizzled
  __shared__ short Blds[2][BN * BK];   // 2 x 32 KiB swizzled

  const char* Bsrc0 = (const char*)Gt + (size_t)(h * NNT + nt) * NKT * TILEB;
  const float* Abase = x + (size_t)(h + 8 * (size_t)mt * BM) * DM;

  float4 ap0[8], ap1[8];   // two A prefetch sets (static-indexed, rule #20)

  auto loadA = [&](int kt, float4 (&ap)[8]) {
    #pragma unroll
    for (int p = 0; p < 4; ++p) {
      int r = (tid >> 3) + 64 * p;
      const float* xr = Abase + (size_t)r * 8 * DM + kt * BK + (tid & 7) * 8;
      ap[2*p]   = *(const float4*)xr;
      ap[2*p+1] = *(const float4*)(xr + 4);
    }
  };
  auto stageB = [&](int kt, int buf) {   // 16 gload_lds per thread-block slice
    const char* src = Bsrc0 + kt * TILEB;
    char* dst = (char*)Blds[buf];
    #pragma unroll
    for (int p = 0; p < 4; ++p)
      __builtin_amdgcn_global_load_lds((const void*)(src + p * 8192 + tid * 16),
                                       (void*)(dst + p * 8192 + wid * 1024), 16, 0, 0);
  };
  auto writeA = [&](float4 (&ap)[8], int buf) {
    char* dst = (char*)Alds[buf];
    #pragma unroll
    for (int p = 0; p < 4; ++p) {
      int r = (tid >> 3) + 64 * p;
      short8 sv;
      sv[0]=f2bf(ap[2*p].x);   sv[1]=f2bf(ap[2*p].y);
      sv[2]=f2bf(ap[2*p].z);   sv[3]=f2bf(ap[2*p].w);
      sv[4]=f2bf(ap[2*p+1].x); sv[5]=f2bf(ap[2*p+1].y);
      sv[6]=f2bf(ap[2*p+1].z); sv[7]=f2bf(ap[2*p+1].w);
      *(short8*)(dst + swz(r, (tid & 7) * 16)) = sv;
    }
  };

  f32x4 acc[8][4] = {};   // wave tile 128x64

  auto computeTile = [&](int cur) {
    const char* Ap = (const char*)Alds[cur];
    const char* Bp = (const char*)Blds[cur];
    #pragma unroll
    for (int ks = 0; ks < 2; ++ks) {
      bf16x8 af[8], bfr[4];
      #pragma unroll
      for (int m = 0; m < 8; ++m)
        af[m] = *(const bf16x8*)(Ap + swz(wr*128 + m*16 + (lane & 15),
                                          ks*64 + (lane >> 4) * 16));
      #pragma unroll
      for (int n = 0; n < 4; ++n)
        bfr[n] = *(const bf16x8*)(Bp + swz(wc*64 + n*16 + (lane & 15),
                                           ks*64 + (lane >> 4) * 16));
      #pragma unroll
      for (int m = 0; m < 8; ++m)
        #pragma unroll
        for (int n = 0; n < 4; ++n)
          acc[m][n] = __builtin_amdgcn_mfma_f32_16x16x32_bf16(af[m], bfr[n], acc[m][n], 0, 0, 0);
    }
  };

  // Boundary: counted vmcnt (T4) — stageB(t+1) [16, older] must land; the 8
  // loadA(t+2) [newer] stay in flight across the barrier.  vmcnt retires
  // in issue order, so vmcnt(8) == "all but the newest 8 done".
#define BOUNDARY(VMSTR)                                                   \
  do {                                                                    \
    asm volatile(VMSTR ::: "memory");                                     \
    __builtin_amdgcn_sched_barrier(0);                                    \
    __builtin_amdgcn_s_barrier();                                         \
    __builtin_amdgcn_sched_barrier(0);                                    \
  } while (0)

#define GITER(T, APC, APN, VMSTR)                                         \
  do {                                                                    \
    if ((T) + 1 < NKT) stageB((T) + 1, ((T) + 1) & 1);                    \
    if ((T) + 2 < NKT) loadA((T) + 2, APC);                               \
    __builtin_amdgcn_sched_barrier(0);                                    \
    computeTile((T) & 1);                                                 \
    if ((T) + 1 < NKT) writeA(APN, ((T) + 1) & 1);                        \
    BOUNDARY(VMSTR);                                                      \
  } while (0)

  // prologue: tile0 -> buf0 staged; tile1 A-loads in flight across barrier
  loadA(0, ap0);
  stageB(0, 0);
  loadA(1, ap1);
  writeA(ap0, 0);          // compiler waits exactly for ap0's 8 loads
  BOUNDARY("s_waitcnt vmcnt(8) lgkmcnt(0)");   // stageB(0) done; loadA(1) flying

  GITER(0, ap0, ap1, "s_waitcnt vmcnt(8) lgkmcnt(0)");
  GITER(1, ap1, ap0, "s_waitcnt vmcnt(8) lgkmcnt(0)");
  GITER(2, ap0, ap1, "s_waitcnt vmcnt(8) lgkmcnt(0)");
  GITER(3, ap1, ap0, "s_waitcnt vmcnt(8) lgkmcnt(0)");
  GITER(4, ap0, ap1, "s_waitcnt vmcnt(8) lgkmcnt(0)");
  GITER(5, ap1, ap0, "s_waitcnt vmcnt(8) lgkmcnt(0)");
  GITER(6, ap0, ap1, "s_waitcnt vmcnt(0) lgkmcnt(0)");  // drain stageB(7)
  computeTile(1);   // t=7: no prefetch, no boundary needed after

#undef GITER
#undef BOUNDARY

  // epilogue: C/D layout col = lane&15, row = (lane>>4)*4 + j
  int e0 = nt * BN + wc * 64 + (lane & 15);
  #pragma unroll
  for (int m = 0; m < 8; ++m) {
    int tq = mt * BM + wr * 128 + m * 16 + ((lane >> 4) << 2);
    #pragma unroll
    for (int j = 0; j < 4; ++j) {
      int R = h + 8 * (tq + j);
      float* orow = out + (size_t)R * DM + e0;
      #pragma unroll
      for (int n = 0; n < 4; ++n)
        orow[n * 16] = acc[m][n][j];
    }
  }
}

extern "C" void kernel_launch(void* const* d_in, const int* in_sizes, int n_in,
                              void* d_out, int out_size, void* d_ws, size_t ws_size,
                              hipStream_t stream) {
  const float* x   = (const float*)d_in[0];
  const float* w   = (const float*)d_in[1];
  const float* fcw = (const float*)d_in[2];
  float* out = (float*)d_out;
  short* Gt  = (short*)d_ws;   // 4 MiB pre-swizzled tile images

  hipLaunchKernelGGL(build_g_kernel, dim3((8 * DM * DM / 8) / 256), dim3(256), 0, stream,
                     w, fcw, Gt);
  hipLaunchKernelGGL(gemm_kernel, dim3(8 * 32 * NNT), dim3(512), 0, stream,
                     x, Gt, out);
}